// Round 1
// baseline (237.906 us; speedup 1.0000x reference)
//
#include <hip/hip_runtime.h>
#include <hip/hip_bf16.h>

namespace {
constexpr int kBatch = 256;
constexpr int kNoise = 128;
constexpr int kIn    = 512;
constexpr int kOut   = 512;
constexpr int kXCols = kNoise + kIn;        // 640
constexpr int kPCols = kIn * kOut + kOut;   // 262656 (W row stride)
constexpr int kOTile = 32;
constexpr int kITile = 16;
constexpr int kFeatsStride = 260;           // padded [i][b] leading dim (mult of 4, breaks 256 stride)
}

typedef __bf16 bf16x8 __attribute__((ext_vector_type(8)));
typedef float  f32x4  __attribute__((ext_vector_type(4)));

// out[b,o] = sum_i feats[b,i]*(noise@W + bvec)[b, i*512+o]
//          + (noise@W + bvec)[b, 262144+o]
// Grid: (512/kOTile=16, 512/kITile=32). Each WG: all 256 batch rows,
// 32 output cols, 16 in-features. W element -> exactly one WG (1x HBM traffic).
__global__ __launch_bounds__(256, 2)
void hyper_gemm_kernel(const float* __restrict__ x,
                       const float* __restrict__ W,
                       const float* __restrict__ bvec,
                       float* __restrict__ out)
{
    const int tid  = threadIdx.x;
    const int lane = tid & 63;
    const int wave = tid >> 6;
    const int q    = lane >> 4;   // quad 0..3
    const int l16  = lane & 15;

    const int o0 = blockIdx.x * kOTile;
    const int i0 = blockIdx.y * kITile;

    __shared__ float feats_lds[kITile * kFeatsStride];

    // Stage feats[b][i0..i0+15] -> feats_lds[i][b] (transposed, padded).
    {
        const int i    = tid & 15;
        const int brow = tid >> 4;
        for (int rep = 0; rep < 16; ++rep) {
            const int b = brow + rep * 16;
            feats_lds[i * kFeatsStride + b] = x[b * kXCols + kNoise + i0 + i];
        }
    }

    // Noise A-fragments, resident in registers for the whole i-loop.
    // Wave covers b in [wave*64, wave*64+64) = 4 m-tiles of 16.
    // 16x16x32 bf16 A layout: A[m = lane&15][k = quad*8 + j], k_global = 32*s + k.
    bf16x8 afrag[4][4];  // [mt][s]
    {
        const int bbase = wave * 64;
        for (int mt = 0; mt < 4; ++mt) {
            const float* xr = x + (bbase + mt * 16 + l16) * kXCols;  // noise row
            for (int s = 0; s < 4; ++s) {
                const float* p = xr + s * 32 + q * 8;
                f32x4 u0 = *(const f32x4*)(p);
                f32x4 u1 = *(const f32x4*)(p + 4);
                bf16x8 a;
                a[0] = (__bf16)u0[0]; a[1] = (__bf16)u0[1];
                a[2] = (__bf16)u0[2]; a[3] = (__bf16)u0[3];
                a[4] = (__bf16)u1[0]; a[5] = (__bf16)u1[1];
                a[6] = (__bf16)u1[2]; a[7] = (__bf16)u1[3];
                afrag[mt][s] = a;
            }
        }
    }

    __syncthreads();

    float oacc[4][2][4];  // [mt][nt][r] -> out-partial, b = wave*64+mt*16+q*4+r, o = o0+nt*16+l16
    for (int mt = 0; mt < 4; ++mt)
        for (int nt = 0; nt < 2; ++nt)
            for (int r = 0; r < 4; ++r) oacc[mt][nt][r] = 0.f;

    // i-tile 0 WGs take one extra pass for the noise@W_bias + b_bias term.
    const int nPass = (blockIdx.y == 0) ? (kITile + 1) : kITile;
    for (int ip = 0; ip < nPass; ++ip) {
        const bool extra = (ip == kITile);
        const int cbase  = extra ? (kIn * kOut) : (i0 + ip) * kOut;

        f32x4 acc[4][2];
        const f32x4 zero = {0.f, 0.f, 0.f, 0.f};
        for (int mt = 0; mt < 4; ++mt)
            for (int nt = 0; nt < 2; ++nt) acc[mt][nt] = zero;

        // Stage-1: acc[b, col] = noise @ W[:, cbase + o0 + col]   (K = 128, 4 MFMA steps)
        #pragma unroll
        for (int s = 0; s < 4; ++s) {
            #pragma unroll
            for (int nt = 0; nt < 2; ++nt) {
                // B layout: B[k = quad*8 + j][col = lane&15]
                const float* wp = W + (size_t)(s * 32 + q * 8) * kPCols
                                    + cbase + o0 + nt * 16 + l16;
                bf16x8 bfrag;
                #pragma unroll
                for (int j = 0; j < 8; ++j)
                    bfrag[j] = (__bf16)wp[(size_t)j * kPCols];
                #pragma unroll
                for (int mt = 0; mt < 4; ++mt)
                    acc[mt][nt] = __builtin_amdgcn_mfma_f32_16x16x32_bf16(
                        afrag[mt][s], bfrag, acc[mt][nt], 0, 0, 0);
            }
        }

        // Stage-2 epilogue (fp32): oacc += feats[b, i] * (acc + bvec[c])
        float bv0 = bvec[cbase + o0 + l16];
        float bv1 = bvec[cbase + o0 + 16 + l16];

        if (!extra) {
            #pragma unroll
            for (int mt = 0; mt < 4; ++mt) {
                // C/D layout: col = lane&15, row = q*4 + reg -> 4 consecutive b
                const f32x4 f4 = *(const f32x4*)&feats_lds[ip * kFeatsStride
                                       + wave * 64 + mt * 16 + q * 4];
                #pragma unroll
                for (int r = 0; r < 4; ++r) {
                    oacc[mt][0][r] += f4[r] * (acc[mt][0][r] + bv0);
                    oacc[mt][1][r] += f4[r] * (acc[mt][1][r] + bv1);
                }
            }
        } else {
            #pragma unroll
            for (int mt = 0; mt < 4; ++mt)
                #pragma unroll
                for (int r = 0; r < 4; ++r) {
                    oacc[mt][0][r] += acc[mt][0][r] + bv0;
                    oacc[mt][1][r] += acc[mt][1][r] + bv1;
                }
        }
    }

    // Combine split-i partials.
    for (int mt = 0; mt < 4; ++mt)
        for (int nt = 0; nt < 2; ++nt) {
            const int o = o0 + nt * 16 + l16;
            #pragma unroll
            for (int r = 0; r < 4; ++r) {
                const int b = wave * 64 + mt * 16 + q * 4 + r;
                atomicAdd(&out[b * kOut + o], oacc[mt][nt][r]);
            }
        }
}

extern "C" void kernel_launch(void* const* d_in, const int* in_sizes, int n_in,
                              void* d_out, int out_size, void* d_ws, size_t ws_size,
                              hipStream_t stream) {
    const float* x  = (const float*)d_in[0];
    const float* W  = (const float*)d_in[1];
    const float* bv = (const float*)d_in[2];
    float* out = (float*)d_out;

    // d_out is poisoned before every call; atomics need zeros.
    hipMemsetAsync(out, 0, (size_t)kBatch * kOut * sizeof(float), stream);

    dim3 grid(kOut / kOTile, kIn / kITile);  // (16, 32) = 512 WGs
    hyper_gemm_kernel<<<grid, 256, 0, stream>>>(x, W, bv, out);
}

// Round 2
// 215.666 us; speedup vs baseline: 1.1031x; 1.1031x over previous
//
#include <hip/hip_runtime.h>
#include <hip/hip_bf16.h>
#include <stdint.h>

namespace {
constexpr int kBatch = 256;
constexpr int kNoise = 128;
constexpr int kIn    = 512;
constexpr int kOut   = 512;
constexpr int kXCols = kNoise + kIn;        // 640
constexpr int kPCols = kIn * kOut + kOut;   // 262656 (W row stride)
constexpr int kOTile = 32;
constexpr int kITile = 16;
constexpr int kWStride = 68;                // LDS col stride in dwords (64 kp + 4 pad)
constexpr int kFeatsStride = 260;
}

typedef __bf16 bf16x8 __attribute__((ext_vector_type(8)));
typedef float  f32x4  __attribute__((ext_vector_type(4)));
typedef unsigned int u32x4 __attribute__((ext_vector_type(4)));

__device__ inline unsigned int pack_bf16x2(float lo, float hi) {
    unsigned int a = (unsigned int)__builtin_bit_cast(unsigned short, (__bf16)lo);
    unsigned int b = (unsigned int)__builtin_bit_cast(unsigned short, (__bf16)hi);
    return a | (b << 16);
}

// Barrier that drains LDS ops only (lgkmcnt(0)) — does NOT drain vmcnt, so
// global prefetch loads issued before it stay in flight (m97's vmcnt(0)
// drain before s_barrier is the stall we're avoiding).
__device__ inline void wg_barrier_lds() {
    __asm__ volatile("" ::: "memory");
    __builtin_amdgcn_s_waitcnt(0xC07F);   // lgkmcnt(0), vmcnt/expcnt = no-wait
    __builtin_amdgcn_s_barrier();
    __asm__ volatile("" ::: "memory");
}

// out[b,o] = sum_i feats[b,i]*(noise@W + bvec)[b, i*512+o] + (noise@W + bvec)[b, 262144+o]
// Grid (16 o-tiles, 32 i-tiles) = 512 WGs x 512 threads (8 waves).
// Each WG: all 256 batch rows, 32 out cols, 16 i-features -> W read exactly once.
__global__ __launch_bounds__(512, 4)
void hyper_gemm_kernel(const float* __restrict__ x,
                       const float* __restrict__ W,
                       const float* __restrict__ bvec,
                       float* __restrict__ out)
{
    const int tid  = threadIdx.x;
    const int lane = tid & 63;
    const int wave = tid >> 6;     // 0..7, owns batch rows [wave*32, wave*32+32)
    const int q    = lane >> 4;
    const int l16  = lane & 15;

    const int o0 = blockIdx.x * kOTile;
    const int i0 = blockIdx.y * kITile;

    // W-tile staging role: thread covers rows {2u, 2u+1}, cols colg..colg+3
    const int u    = tid >> 3;          // 0..63  (kp index)
    const int colg = (tid & 7) * 4;

    __shared__ unsigned int wtile[kOTile * kWStride];          // bf16-pair tile [col][kp]
    __shared__ float feats_lds[kITile * kFeatsStride];         // [i][b] transposed

    // ---- one-time staging ----
    {   // feats[b][i0+i] -> feats_lds[i][b]
        const int i    = tid & 15;
        const int brow = tid >> 4;      // 0..31
        #pragma unroll
        for (int rep = 0; rep < 8; ++rep) {
            const int b = brow + rep * 32;
            feats_lds[i * kFeatsStride + b] = x[b * kXCols + kNoise + i0 + i];
        }
    }

    // Noise A-fragments (resident): wave rows base wave*32, 2 m-tiles of 16.
    // A layout: A[m=lane&15][k=q*8+j], k_global = 32*s + k.
    bf16x8 afrag[2][4];
    {
        #pragma unroll
        for (int mt = 0; mt < 2; ++mt) {
            const float* xr = x + (size_t)(wave * 32 + mt * 16 + l16) * kXCols;
            #pragma unroll
            for (int s = 0; s < 4; ++s) {
                const float* p = xr + s * 32 + q * 8;
                f32x4 u0 = *(const f32x4*)(p);
                f32x4 u1 = *(const f32x4*)(p + 4);
                bf16x8 a;
                a[0] = (__bf16)u0[0]; a[1] = (__bf16)u0[1];
                a[2] = (__bf16)u0[2]; a[3] = (__bf16)u0[3];
                a[4] = (__bf16)u1[0]; a[5] = (__bf16)u1[1];
                a[6] = (__bf16)u1[2]; a[7] = (__bf16)u1[3];
                afrag[mt][s] = a;
            }
        }
    }

    float oacc[2][2][4];   // [mt][nt][r]; b = wave*32+mt*16+q*4+r, o = o0+nt*16+l16
    #pragma unroll
    for (int mt = 0; mt < 2; ++mt)
        #pragma unroll
        for (int nt = 0; nt < 2; ++nt)
            #pragma unroll
            for (int r = 0; r < 4; ++r) oacc[mt][nt][r] = 0.f;

    __syncthreads();   // feats ready; also drains one-time loads

    const int nPass = (blockIdx.y == 0) ? (kITile + 1) : kITile;

    auto pass_cbase = [&](int p) -> int {
        return (p == kITile) ? (kIn * kOut) : (i0 + p) * kOut;
    };

    // ---- software-pipelined i-loop ----
    f32x4 pr0, pr1;   // prefetched W rows (2u, 2u+1), 4 cols
    {
        const float* wp = W + (size_t)(2 * u) * kPCols + pass_cbase(0) + o0 + colg;
        pr0 = *(const f32x4*)wp;
        pr1 = *(const f32x4*)(wp + kPCols);
    }

    for (int ip = 0; ip < nPass; ++ip) {
        const int cbase = pass_cbase(ip);

        // pack previously-prefetched tile (vmcnt wait lands here, overlapped
        // with previous pass's MFMA phase)
        unsigned int pk[4];
        #pragma unroll
        for (int cc = 0; cc < 4; ++cc) pk[cc] = pack_bf16x2(pr0[cc], pr1[cc]);

        wg_barrier_lds();          // previous tile's fragment reads complete
        #pragma unroll
        for (int cc = 0; cc < 4; ++cc)
            wtile[(colg + cc) * kWStride + u] = pk[cc];

        // issue next-pass prefetch NOW — rides through the (non-draining) barrier
        if (ip + 1 < nPass) {
            const float* wp = W + (size_t)(2 * u) * kPCols + pass_cbase(ip + 1) + o0 + colg;
            pr0 = *(const f32x4*)wp;
            pr1 = *(const f32x4*)(wp + kPCols);
        }

        wg_barrier_lds();          // tile visible to all waves

        // Stage-1 GEMM: acc[b, col] = noise @ W[:, cbase+o0+col]
        f32x4 acc[2][2];
        const f32x4 zero = {0.f, 0.f, 0.f, 0.f};
        #pragma unroll
        for (int mt = 0; mt < 2; ++mt)
            #pragma unroll
            for (int nt = 0; nt < 2; ++nt) acc[mt][nt] = zero;

        #pragma unroll
        for (int s = 0; s < 4; ++s) {
            #pragma unroll
            for (int nt = 0; nt < 2; ++nt) {
                // B layout [k=q*8+j][col=l16]: 4 consecutive uints = 8 bf16 (k asc)
                u32x4 raw = *(const u32x4*)&wtile[(nt * 16 + l16) * kWStride + s * 16 + q * 4];
                bf16x8 bfrag = __builtin_bit_cast(bf16x8, raw);
                #pragma unroll
                for (int mt = 0; mt < 2; ++mt)
                    acc[mt][nt] = __builtin_amdgcn_mfma_f32_16x16x32_bf16(
                        afrag[mt][s], bfrag, acc[mt][nt], 0, 0, 0);
            }
        }

        // Stage-2 epilogue (fp32): oacc += feats[b,i] * (acc + bvec[c])
        const float bv0 = bvec[cbase + o0 + l16];
        const float bv1 = bvec[cbase + o0 + 16 + l16];

        if (ip < kITile) {
            #pragma unroll
            for (int mt = 0; mt < 2; ++mt) {
                // C/D layout: col = lane&15, row = q*4 + reg
                const f32x4 f4 = *(const f32x4*)&feats_lds[ip * kFeatsStride
                                        + wave * 32 + mt * 16 + q * 4];
                #pragma unroll
                for (int r = 0; r < 4; ++r) {
                    oacc[mt][0][r] += f4[r] * (acc[mt][0][r] + bv0);
                    oacc[mt][1][r] += f4[r] * (acc[mt][1][r] + bv1);
                }
            }
        } else {   // bias-term pass (blockIdx.y == 0 only), scale = 1
            #pragma unroll
            for (int mt = 0; mt < 2; ++mt)
                #pragma unroll
                for (int r = 0; r < 4; ++r) {
                    oacc[mt][0][r] += acc[mt][0][r] + bv0;
                    oacc[mt][1][r] += acc[mt][1][r] + bv1;
                }
        }
    }

    // combine split-i partials
    #pragma unroll
    for (int mt = 0; mt < 2; ++mt)
        #pragma unroll
        for (int nt = 0; nt < 2; ++nt) {
            const int o = o0 + nt * 16 + l16;
            #pragma unroll
            for (int r = 0; r < 4; ++r) {
                const int b = wave * 32 + mt * 16 + q * 4 + r;
                atomicAdd(&out[b * kOut + o], oacc[mt][nt][r]);
            }
        }
}

extern "C" void kernel_launch(void* const* d_in, const int* in_sizes, int n_in,
                              void* d_out, int out_size, void* d_ws, size_t ws_size,
                              hipStream_t stream) {
    const float* x  = (const float*)d_in[0];
    const float* W  = (const float*)d_in[1];
    const float* bv = (const float*)d_in[2];
    float* out = (float*)d_out;

    hipMemsetAsync(out, 0, (size_t)kBatch * kOut * sizeof(float), stream);

    dim3 grid(kOut / kOTile, kIn / kITile);  // (16, 32) = 512 WGs of 512 threads
    hyper_gemm_kernel<<<grid, 512, 0, stream>>>(x, W, bv, out);
}